// Round 13
// baseline (160.579 us; speedup 1.0000x reference)
//
#include <hip/hip_runtime.h>

// ---------------------------------------------------------------------------
// Tree_42520176230890 (v13 = v12 with native-vector NT stores):
//   prep_w:   idx extract + Wt = bf16(W^T)        (merged, validated v9)
//   gather:   feats[r][k] = bf16(x[r][idx[k]])    (LDS-staged, validated v9)
//   gemm256:  d = sigmoid(feats @ W + b) -> bf16 into out cols[1536:2048)
//             (256x256, counted-vmcnt 8-phase, validated v11)
//   expand:   tree expansion, 1 row/wave; XCD-matched row swizzle so d reads
//             hit the L2 that gemm wrote; nontemporal out stores (ext-vector).
// ---------------------------------------------------------------------------

typedef __bf16 bf16x8 __attribute__((ext_vector_type(8)));
typedef float  f32x4  __attribute__((ext_vector_type(4)));
typedef float  f32x2  __attribute__((ext_vector_type(2)));

#define BATCH 16384
#define NLEAF 1024
#define FEAT  1024
#define OUTC  2048

__device__ __forceinline__ unsigned short f2bf(float f) {
    union { float f; unsigned int u; } c; c.f = f;
    unsigned int u = c.u;
    u += 0x7FFFu + ((u >> 16) & 1u);   // RNE
    return (unsigned short)(u >> 16);
}

__device__ __forceinline__ float bf2f(unsigned short u) {
    union { unsigned int i; float f; } c; c.i = (unsigned int)u << 16;
    return c.f;
}

__device__ __forceinline__ void load_lds16(const void* g, void* l) {
    __builtin_amdgcn_global_load_lds(
        (const __attribute__((address_space(1))) unsigned int*)g,
        (__attribute__((address_space(3))) unsigned int*)l, 16, 0, 0);
}

__device__ __forceinline__ float sigmoidf(float z) {
    return 1.0f / (1.0f + __expf(-z));
}

__device__ __forceinline__ void nt_store4(float* p, float a, float b,
                                          float c, float d) {
    f32x4 v = { a, b, c, d };
    __builtin_nontemporal_store(v, (f32x4*)p);
}
__device__ __forceinline__ void nt_store2(float* p, float a, float b) {
    f32x2 v = { a, b };
    __builtin_nontemporal_store(v, (f32x2*)p);
}

// --- 1. merged: idx extract (blocks 0..1023) + W transpose (1024..1279) ----
__global__ __launch_bounds__(256) void prep_w(const float* __restrict__ fm,
                                              const float* __restrict__ W,
                                              int* __restrict__ idx,
                                              short* __restrict__ Wt) {
    __shared__ short tile[64][65];
    const int b = blockIdx.x, t = threadIdx.x;
    if (b < 1024) {
        const int f = b;
#pragma unroll
        for (int i = 0; i < 4; ++i) {
            int leaf = i * 256 + t;
            if (fm[(size_t)f * NLEAF + leaf] > 0.5f) idx[leaf] = f;
        }
    } else {
        const int tb = b - 1024;
        const int k0 = (tb >> 4) * 64, n0 = (tb & 15) * 64;
#pragma unroll
        for (int i = 0; i < 16; ++i) {
            int e = i * 256 + t;
            int kr = e >> 6, nc = e & 63;
            tile[kr][nc] = (short)f2bf(W[(size_t)(k0 + kr) * NLEAF + n0 + nc]);
        }
        __syncthreads();
#pragma unroll
        for (int i = 0; i < 16; ++i) {
            int e = i * 256 + t;
            int nr = e >> 6, kc = e & 63;
            Wt[(size_t)(n0 + nr) * FEAT + k0 + kc] = tile[kc][nr];
        }
    }
}

// --- 2. LDS-staged gather (validated v9) -----------------------------------
__global__ __launch_bounds__(256) void gather_feats(const float* __restrict__ x,
                                                    const int* __restrict__ idx,
                                                    short* __restrict__ feats) {
    __shared__ float xs[8][1024];
    __shared__ int   ids[1024];
    const int t = threadIdx.x;
    const int r0 = blockIdx.x * 8;

    {
        int4 v = ((const int4*)idx)[t];
        *(int4*)&ids[t * 4] = v;
    }
#pragma unroll
    for (int j = 0; j < 8; ++j) {
        int e = j * 256 + t;
        int row = e >> 8, c4 = e & 255;
        ((float4*)xs[row])[c4] =
            ((const float4*)(x + (size_t)(r0 + row) * FEAT))[c4];
    }
    __syncthreads();

#pragma unroll
    for (int j = 0; j < 4; ++j) {
        int e = j * 256 + t;
        int row = e >> 7, kk = (e & 127) * 8;
        union { short s[8]; int4 v; } pk;
#pragma unroll
        for (int q = 0; q < 8; ++q)
            pk.s[q] = (short)f2bf(xs[row][ids[kk + q]]);
        *(int4*)(feats + (size_t)(r0 + row) * FEAT + kk) = pk.v;
    }
}

// --- 3. GEMM 256x256, counted-vmcnt 8-phase (validated v11) ----------------
#define STAGEH(MAT, KH, TT, BUFN)                                             \
    {                                                                         \
        _Pragma("unroll")                                                     \
        for (int j = 0; j < 2; ++j) {                                         \
            const int slotidx = j * 512 + tid;                                \
            const int srow = slotidx >> 2;                                    \
            const short* srcb = (MAT) ? (Wt + (size_t)(n0 + srow) * FEAT)     \
                                      : (feats + (size_t)(row0 + srow) * FEAT);\
            load_lds16(srcb + ((TT) << 6) + ((KH) << 5) + (ssrc << 3),        \
                       smem + (MAT) * 65536 + (BUFN) * 32768                  \
                            + (KH) * 16384 + slotidx * 16);                   \
        }                                                                     \
    }

// WAITV: 0 = none, 1 = vmcnt(4), 2 = vmcnt(0)
#define GPHASE(QM, KH, DO_STAGE, SMAT, SKH, WAITV)                            \
    {                                                                         \
        bf16x8 av[4];                                                         \
        _Pragma("unroll")                                                     \
        for (int mm = 0; mm < 4; ++mm)                                        \
            av[mm] = *(const bf16x8*)(smem + bufA + (KH) * 16384              \
                                      + aRow[(QM) * 4 + mm]);                 \
        if ((QM) == 0) {                                                      \
            _Pragma("unroll")                                                 \
            for (int nn = 0; nn < 4; ++nn)                                    \
                bvk[nn] = *(const bf16x8*)(smem + bufA + (KH) * 16384         \
                                           + bRow[nn]);                       \
        }                                                                     \
        if (DO_STAGE) STAGEH(SMAT, SKH, t + 1, bufN);                         \
        __builtin_amdgcn_s_barrier();                                         \
        asm volatile("s_waitcnt lgkmcnt(0)" ::: "memory");                    \
        __builtin_amdgcn_sched_barrier(0);                                    \
        __builtin_amdgcn_s_setprio(1);                                        \
        _Pragma("unroll")                                                     \
        for (int mm = 0; mm < 4; ++mm)                                        \
            _Pragma("unroll")                                                 \
            for (int nn = 0; nn < 4; ++nn)                                    \
                acc[(QM) * 4 + mm][nn] =                                      \
                    __builtin_amdgcn_mfma_f32_16x16x32_bf16(                  \
                        av[mm], bvk[nn], acc[(QM) * 4 + mm][nn], 0, 0, 0);    \
        __builtin_amdgcn_s_setprio(0);                                        \
        if ((WAITV) == 1) { asm volatile("s_waitcnt vmcnt(4)" ::: "memory"); }\
        if ((WAITV) == 2) { asm volatile("s_waitcnt vmcnt(0)" ::: "memory"); }\
        __builtin_amdgcn_s_barrier();                                         \
    }

__global__ __launch_bounds__(512, 2) void gemm256_sig_d(
        const short* __restrict__ feats, const short* __restrict__ Wt,
        const float* __restrict__ bias, unsigned short* __restrict__ dout) {
    __shared__ __align__(16) char smem_[131072];
    char* smem = smem_;

    const int tid = threadIdx.x, l = tid & 63, w = tid >> 6;
    const int wr = w >> 2, wc = w & 3;             // 2M x 4N wave grid
    const int lr = l & 15, lk = l >> 4;            // lk in 0..3 (4 slot16/kh)
    const int bid = blockIdx.x;
    const int swz = (bid & 7) * 32 + (bid >> 3);   // 256 = 8 XCD x 32
    const int row0 = (swz >> 2) << 8;              // 64 M-tiles
    const int n0   = (swz & 3) << 8;               // 4 N-tiles

    const int ssrc = (tid & 3) ^ ((tid >> 3) & 3);

    const int slotoff = (lk ^ ((lr >> 1) & 3)) << 4;
    int aRow[8], bRow[4];
#pragma unroll
    for (int m = 0; m < 8; ++m)
        aRow[m] = (wr * 128 + m * 16 + lr) * 64 + slotoff;
#pragma unroll
    for (int n = 0; n < 4; ++n)
        bRow[n] = 65536 + (wc * 64 + n * 16 + lr) * 64 + slotoff;

    float bvreg[4];
#pragma unroll
    for (int n = 0; n < 4; ++n)
        bvreg[n] = bias[n0 + wc * 64 + n * 16 + lr];

    f32x4 acc[8][4];
#pragma unroll
    for (int m = 0; m < 8; ++m)
#pragma unroll
        for (int n = 0; n < 4; ++n)
#pragma unroll
            for (int r = 0; r < 4; ++r) acc[m][n][r] = 0.0f;

    {
        const int t = -1, bufN = 0;
        STAGEH(0, 0, t + 1, bufN);
        STAGEH(1, 0, t + 1, bufN);
        STAGEH(0, 1, t + 1, bufN);
        STAGEH(1, 1, t + 1, bufN);
    }
    asm volatile("s_waitcnt vmcnt(4)" ::: "memory");
    __builtin_amdgcn_s_barrier();

    bf16x8 bvk[4];
    for (int t = 0; t < 15; ++t) {
        const int bufA = (t & 1) * 32768;
        const int bufN = (t & 1) ^ 1;
        GPHASE(0, 0, true, 0, 0, 0);
        GPHASE(1, 0, true, 1, 0, 1);
        GPHASE(0, 1, true, 0, 1, 0);
        GPHASE(1, 1, true, 1, 1, 1);
    }
    {
        const int t = 15;
        const int bufA = 32768, bufN = 0;
        (void)bufN;
        GPHASE(0, 0, false, 0, 0, 0);
        GPHASE(1, 0, false, 1, 0, 2);
        GPHASE(0, 1, false, 0, 1, 0);
        GPHASE(1, 1, false, 1, 1, 0);
    }

#pragma unroll
    for (int m = 0; m < 8; ++m) {
#pragma unroll
        for (int n = 0; n < 4; ++n) {
            const int col = n0 + wc * 64 + n * 16 + lr;
#pragma unroll
            for (int rr = 0; rr < 4; ++rr) {
                const int row = row0 + wr * 128 + m * 16 + lk * 4 + rr;
                dout[(size_t)row * 4096 + 3072 + col] =
                    f2bf(sigmoidf(acc[m][n][rr] + bvreg[n]));
            }
        }
    }
}

// --- 4. tree expansion: 1 row/wave; XCD-matched rows + NT stores -----------
// gemm XCD c wrote d rows [c*2048,(c+1)*2048) into its L2 (4 MiB = L2 size).
// Expand block eb lands on XCD eb&7 (round-robin heuristic); swizzle
// eb' = (eb&7)*512 + (eb>>3) makes its rows come from that same range.
// Final out stores nontemporal: out is never re-read; preserves d in L2.
__global__ __launch_bounds__(256) void expand_tree(float* __restrict__ out) {
    const int t = threadIdx.x, l = t & 63, w = t >> 6;
    const int eb = blockIdx.x;
    const int ebs = (eb & 7) * 512 + (eb >> 3);    // bijective, 4096 = 8*512
    const int row = ebs * 4 + w;
    const unsigned short* dr =
        (const unsigned short*)out + (size_t)row * 4096 + 3072;
    float* orow = out + (size_t)row * OUTC;

    // ---- load ALL d into registers first ----------------------------------
    float dpath[6];
#pragma unroll
    for (int j = 0; j <= 5; ++j) {
        int idx = l >> (5 - j);
        dpath[j] = bf2f(dr[(1 << j) + (idx >> 1)]);
    }
    float d6 = bf2f(dr[64 + l]);
    unsigned int u7 = *(const unsigned int*)(dr + 128 + 2 * l);
    float d7[2] = { bf2f((unsigned short)(u7 & 0xffff)),
                    bf2f((unsigned short)(u7 >> 16)) };
    uint2 u8 = *(const uint2*)(dr + 256 + 4 * l);
    float d8[4] = { bf2f((unsigned short)(u8.x & 0xffff)),
                    bf2f((unsigned short)(u8.x >> 16)),
                    bf2f((unsigned short)(u8.y & 0xffff)),
                    bf2f((unsigned short)(u8.y >> 16)) };
    uint4 u9 = *(const uint4*)(dr + 512 + 8 * l);
    float d9[8] = { bf2f((unsigned short)(u9.x & 0xffff)),
                    bf2f((unsigned short)(u9.x >> 16)),
                    bf2f((unsigned short)(u9.y & 0xffff)),
                    bf2f((unsigned short)(u9.y >> 16)),
                    bf2f((unsigned short)(u9.z & 0xffff)),
                    bf2f((unsigned short)(u9.z >> 16)),
                    bf2f((unsigned short)(u9.w & 0xffff)),
                    bf2f((unsigned short)(u9.w >> 16)) };

    // ---- compute + store (nontemporal) ------------------------------------
    float p = 1.0f;
#pragma unroll
    for (int j = 0; j <= 5; ++j) {
        int idx = l >> (5 - j);
        p *= (idx & 1) ? (1.0f - dpath[j]) : dpath[j];
        if ((l & ((1 << (5 - j)) - 1)) == 0)
            __builtin_nontemporal_store(p, &orow[(2 << j) + idx]);
    }
    if (l < 2) __builtin_nontemporal_store(1.0f, &orow[l]);

    float v6[2] = { p * d6, p * (1.0f - d6) };
    nt_store2(orow + 128 + 2 * l, v6[0], v6[1]);

    float v7[4];
#pragma unroll
    for (int e = 0; e < 4; ++e)
        v7[e] = v6[e >> 1] * ((e & 1) ? (1.0f - d7[e >> 1]) : d7[e >> 1]);
    nt_store4(orow + 256 + 4 * l, v7[0], v7[1], v7[2], v7[3]);

    float v8[8];
#pragma unroll
    for (int e = 0; e < 8; ++e)
        v8[e] = v7[e >> 1] * ((e & 1) ? (1.0f - d8[e >> 1]) : d8[e >> 1]);
    nt_store4(orow + 512 + 8 * l,     v8[0], v8[1], v8[2], v8[3]);
    nt_store4(orow + 512 + 8 * l + 4, v8[4], v8[5], v8[6], v8[7]);

    float v9[16];
#pragma unroll
    for (int e = 0; e < 16; ++e)
        v9[e] = v8[e >> 1] * ((e & 1) ? (1.0f - d9[e >> 1]) : d9[e >> 1]);
#pragma unroll
    for (int q = 0; q < 4; ++q)
        nt_store4(orow + 1024 + 16 * l + 4 * q,
                  v9[4*q], v9[4*q+1], v9[4*q+2], v9[4*q+3]);
}

// --- fallback (tiny workspace): naive fused, one row per block -------------
template <bool HAS_IDX>
__global__ __launch_bounds__(256) void fused_naive(const float* __restrict__ x,
                                                   const float* __restrict__ fm,
                                                   const float* __restrict__ W,
                                                   const float* __restrict__ bias,
                                                   const int* __restrict__ idx,
                                                   float* __restrict__ out) {
    __shared__ float fx[1024];
    __shared__ float dsm[1024];
    __shared__ float tre[2048];
    __shared__ int   idl[1024];
    const int t = threadIdx.x;
    const int row = blockIdx.x;

    if (HAS_IDX) {
        for (int k = t; k < 1024; k += 256) idl[k] = idx[k];
    } else {
        for (int k = t; k < 1024; k += 256) {
            int found = 0;
            for (int f = 0; f < 1024; ++f)
                if (fm[(size_t)f * NLEAF + k] > 0.5f) found = f;
            idl[k] = found;
        }
    }
    __syncthreads();
    const float* xr = x + (size_t)row * FEAT;
    for (int k = t; k < 1024; k += 256) fx[k] = xr[idl[k]];
    __syncthreads();

    float a0 = 0.f, a1 = 0.f, a2 = 0.f, a3 = 0.f;
    for (int k = 0; k < 1024; ++k) {
        float f = fx[k];
        const float* wrp = W + (size_t)k * NLEAF + t;
        a0 = fmaf(f, wrp[0],   a0);
        a1 = fmaf(f, wrp[256], a1);
        a2 = fmaf(f, wrp[512], a2);
        a3 = fmaf(f, wrp[768], a3);
    }
    dsm[t]       = sigmoidf(a0 + bias[t]);
    dsm[t + 256] = sigmoidf(a1 + bias[t + 256]);
    dsm[t + 512] = sigmoidf(a2 + bias[t + 512]);
    dsm[t + 768] = sigmoidf(a3 + bias[t + 768]);
    if (t < 2) tre[t] = 1.0f;
    __syncthreads();

    for (int L = 0; L < 10; ++L) {
        int n = 2 << L;
        for (int k = t; k < n; k += 256) {
            int node = (1 << L) + (k >> 1);
            float dv = dsm[node];
            tre[n + k] = tre[node] * ((k & 1) ? (1.0f - dv) : dv);
        }
        __syncthreads();
    }
    float4* orow = (float4*)(out + (size_t)row * OUTC);
    const float4* ts = (const float4*)tre;
    for (int i = t; i < 512; i += 256) orow[i] = ts[i];
}

extern "C" void kernel_launch(void* const* d_in, const int* in_sizes, int n_in,
                              void* d_out, int out_size, void* d_ws, size_t ws_size,
                              hipStream_t stream) {
    const float* x    = (const float*)d_in[0];
    const float* fm   = (const float*)d_in[1];
    const float* W    = (const float*)d_in[2];
    const float* bias = (const float*)d_in[3];
    float* out = (float*)d_out;

    const size_t IDX_B   = 4096;
    const size_t WT_B    = (size_t)NLEAF * FEAT * 2;        // 2 MiB
    const size_t FEATS_B = (size_t)BATCH * FEAT * 2;        // 32 MiB
    const size_t need = IDX_B + WT_B + FEATS_B;

    if (ws_size >= need) {
        int*   idx   = (int*)d_ws;
        short* Wt    = (short*)((char*)d_ws + IDX_B);
        short* feats = (short*)((char*)d_ws + IDX_B + WT_B);

        prep_w<<<1280, 256, 0, stream>>>(fm, W, idx, Wt);
        gather_feats<<<BATCH / 8, 256, 0, stream>>>(x, idx, feats);
        gemm256_sig_d<<<(BATCH / 256) * (NLEAF / 256), 512, 0, stream>>>(
            feats, Wt, bias, (unsigned short*)out);
        expand_tree<<<BATCH / 4, 256, 0, stream>>>(out);
    } else if (ws_size >= IDX_B) {
        int* idx = (int*)d_ws;
        prep_w<<<1280, 256, 0, stream>>>(fm, nullptr, idx, nullptr);
        fused_naive<true><<<BATCH, 256, 0, stream>>>(x, fm, W, bias, idx, out);
    } else {
        fused_naive<false><<<BATCH, 256, 0, stream>>>(x, fm, W, bias, nullptr, out);
    }
}

// Round 14
// 95.945 us; speedup vs baseline: 1.6737x; 1.6737x over previous
//
#include <hip/hip_runtime.h>

// ---------------------------------------------------------------------------
// Tree_42520176230890 (v14 = v11 + XCD-matched expand rows; NT stores REVERTED
//   after v13's counter-proven 1.6x write amplification):
//   prep_w:   idx extract + Wt = bf16(W^T)        (merged, validated v9)
//   gather:   feats[r][k] = bf16(x[r][idx[k]])    (LDS-staged, validated v9)
//   gemm256:  d = sigmoid(feats @ W + b) -> bf16 into out cols[1536:2048)
//             (256x256, counted-vmcnt 8-phase, validated v11)
//   expand:   tree expansion, 1 row/wave, plain stores; XCD-matched row
//             swizzle so d reads hit the L2 the gemm wrote.
// ---------------------------------------------------------------------------

typedef __bf16 bf16x8 __attribute__((ext_vector_type(8)));
typedef float  f32x4  __attribute__((ext_vector_type(4)));

#define BATCH 16384
#define NLEAF 1024
#define FEAT  1024
#define OUTC  2048

__device__ __forceinline__ unsigned short f2bf(float f) {
    union { float f; unsigned int u; } c; c.f = f;
    unsigned int u = c.u;
    u += 0x7FFFu + ((u >> 16) & 1u);   // RNE
    return (unsigned short)(u >> 16);
}

__device__ __forceinline__ float bf2f(unsigned short u) {
    union { unsigned int i; float f; } c; c.i = (unsigned int)u << 16;
    return c.f;
}

__device__ __forceinline__ void load_lds16(const void* g, void* l) {
    __builtin_amdgcn_global_load_lds(
        (const __attribute__((address_space(1))) unsigned int*)g,
        (__attribute__((address_space(3))) unsigned int*)l, 16, 0, 0);
}

__device__ __forceinline__ float sigmoidf(float z) {
    return 1.0f / (1.0f + __expf(-z));
}

// --- 1. merged: idx extract (blocks 0..1023) + W transpose (1024..1279) ----
__global__ __launch_bounds__(256) void prep_w(const float* __restrict__ fm,
                                              const float* __restrict__ W,
                                              int* __restrict__ idx,
                                              short* __restrict__ Wt) {
    __shared__ short tile[64][65];
    const int b = blockIdx.x, t = threadIdx.x;
    if (b < 1024) {
        const int f = b;
#pragma unroll
        for (int i = 0; i < 4; ++i) {
            int leaf = i * 256 + t;
            if (fm[(size_t)f * NLEAF + leaf] > 0.5f) idx[leaf] = f;
        }
    } else {
        const int tb = b - 1024;
        const int k0 = (tb >> 4) * 64, n0 = (tb & 15) * 64;
#pragma unroll
        for (int i = 0; i < 16; ++i) {
            int e = i * 256 + t;
            int kr = e >> 6, nc = e & 63;
            tile[kr][nc] = (short)f2bf(W[(size_t)(k0 + kr) * NLEAF + n0 + nc]);
        }
        __syncthreads();
#pragma unroll
        for (int i = 0; i < 16; ++i) {
            int e = i * 256 + t;
            int nr = e >> 6, kc = e & 63;
            Wt[(size_t)(n0 + nr) * FEAT + k0 + kc] = tile[kc][nr];
        }
    }
}

// --- 2. LDS-staged gather (validated v9) -----------------------------------
__global__ __launch_bounds__(256) void gather_feats(const float* __restrict__ x,
                                                    const int* __restrict__ idx,
                                                    short* __restrict__ feats) {
    __shared__ float xs[8][1024];
    __shared__ int   ids[1024];
    const int t = threadIdx.x;
    const int r0 = blockIdx.x * 8;

    {
        int4 v = ((const int4*)idx)[t];
        *(int4*)&ids[t * 4] = v;
    }
#pragma unroll
    for (int j = 0; j < 8; ++j) {
        int e = j * 256 + t;
        int row = e >> 8, c4 = e & 255;
        ((float4*)xs[row])[c4] =
            ((const float4*)(x + (size_t)(r0 + row) * FEAT))[c4];
    }
    __syncthreads();

#pragma unroll
    for (int j = 0; j < 4; ++j) {
        int e = j * 256 + t;
        int row = e >> 7, kk = (e & 127) * 8;
        union { short s[8]; int4 v; } pk;
#pragma unroll
        for (int q = 0; q < 8; ++q)
            pk.s[q] = (short)f2bf(xs[row][ids[kk + q]]);
        *(int4*)(feats + (size_t)(r0 + row) * FEAT + kk) = pk.v;
    }
}

// --- 3. GEMM 256x256, counted-vmcnt 8-phase (validated v11) ----------------
#define STAGEH(MAT, KH, TT, BUFN)                                             \
    {                                                                         \
        _Pragma("unroll")                                                     \
        for (int j = 0; j < 2; ++j) {                                         \
            const int slotidx = j * 512 + tid;                                \
            const int srow = slotidx >> 2;                                    \
            const short* srcb = (MAT) ? (Wt + (size_t)(n0 + srow) * FEAT)     \
                                      : (feats + (size_t)(row0 + srow) * FEAT);\
            load_lds16(srcb + ((TT) << 6) + ((KH) << 5) + (ssrc << 3),        \
                       smem + (MAT) * 65536 + (BUFN) * 32768                  \
                            + (KH) * 16384 + slotidx * 16);                   \
        }                                                                     \
    }

// WAITV: 0 = none, 1 = vmcnt(4), 2 = vmcnt(0)
#define GPHASE(QM, KH, DO_STAGE, SMAT, SKH, WAITV)                            \
    {                                                                         \
        bf16x8 av[4];                                                         \
        _Pragma("unroll")                                                     \
        for (int mm = 0; mm < 4; ++mm)                                        \
            av[mm] = *(const bf16x8*)(smem + bufA + (KH) * 16384              \
                                      + aRow[(QM) * 4 + mm]);                 \
        if ((QM) == 0) {                                                      \
            _Pragma("unroll")                                                 \
            for (int nn = 0; nn < 4; ++nn)                                    \
                bvk[nn] = *(const bf16x8*)(smem + bufA + (KH) * 16384         \
                                           + bRow[nn]);                       \
        }                                                                     \
        if (DO_STAGE) STAGEH(SMAT, SKH, t + 1, bufN);                         \
        __builtin_amdgcn_s_barrier();                                         \
        asm volatile("s_waitcnt lgkmcnt(0)" ::: "memory");                    \
        __builtin_amdgcn_sched_barrier(0);                                    \
        __builtin_amdgcn_s_setprio(1);                                        \
        _Pragma("unroll")                                                     \
        for (int mm = 0; mm < 4; ++mm)                                        \
            _Pragma("unroll")                                                 \
            for (int nn = 0; nn < 4; ++nn)                                    \
                acc[(QM) * 4 + mm][nn] =                                      \
                    __builtin_amdgcn_mfma_f32_16x16x32_bf16(                  \
                        av[mm], bvk[nn], acc[(QM) * 4 + mm][nn], 0, 0, 0);    \
        __builtin_amdgcn_s_setprio(0);                                        \
        if ((WAITV) == 1) { asm volatile("s_waitcnt vmcnt(4)" ::: "memory"); }\
        if ((WAITV) == 2) { asm volatile("s_waitcnt vmcnt(0)" ::: "memory"); }\
        __builtin_amdgcn_s_barrier();                                         \
    }

__global__ __launch_bounds__(512, 2) void gemm256_sig_d(
        const short* __restrict__ feats, const short* __restrict__ Wt,
        const float* __restrict__ bias, unsigned short* __restrict__ dout) {
    __shared__ __align__(16) char smem_[131072];
    char* smem = smem_;

    const int tid = threadIdx.x, l = tid & 63, w = tid >> 6;
    const int wr = w >> 2, wc = w & 3;             // 2M x 4N wave grid
    const int lr = l & 15, lk = l >> 4;            // lk in 0..3 (4 slot16/kh)
    const int bid = blockIdx.x;
    const int swz = (bid & 7) * 32 + (bid >> 3);   // 256 = 8 XCD x 32
    const int row0 = (swz >> 2) << 8;              // 64 M-tiles
    const int n0   = (swz & 3) << 8;               // 4 N-tiles

    const int ssrc = (tid & 3) ^ ((tid >> 3) & 3);

    const int slotoff = (lk ^ ((lr >> 1) & 3)) << 4;
    int aRow[8], bRow[4];
#pragma unroll
    for (int m = 0; m < 8; ++m)
        aRow[m] = (wr * 128 + m * 16 + lr) * 64 + slotoff;
#pragma unroll
    for (int n = 0; n < 4; ++n)
        bRow[n] = 65536 + (wc * 64 + n * 16 + lr) * 64 + slotoff;

    float bvreg[4];
#pragma unroll
    for (int n = 0; n < 4; ++n)
        bvreg[n] = bias[n0 + wc * 64 + n * 16 + lr];

    f32x4 acc[8][4];
#pragma unroll
    for (int m = 0; m < 8; ++m)
#pragma unroll
        for (int n = 0; n < 4; ++n)
#pragma unroll
            for (int r = 0; r < 4; ++r) acc[m][n][r] = 0.0f;

    {
        const int t = -1, bufN = 0;
        STAGEH(0, 0, t + 1, bufN);
        STAGEH(1, 0, t + 1, bufN);
        STAGEH(0, 1, t + 1, bufN);
        STAGEH(1, 1, t + 1, bufN);
    }
    asm volatile("s_waitcnt vmcnt(4)" ::: "memory");
    __builtin_amdgcn_s_barrier();

    bf16x8 bvk[4];
    for (int t = 0; t < 15; ++t) {
        const int bufA = (t & 1) * 32768;
        const int bufN = (t & 1) ^ 1;
        GPHASE(0, 0, true, 0, 0, 0);
        GPHASE(1, 0, true, 1, 0, 1);
        GPHASE(0, 1, true, 0, 1, 0);
        GPHASE(1, 1, true, 1, 1, 1);
    }
    {
        const int t = 15;
        const int bufA = 32768, bufN = 0;
        (void)bufN;
        GPHASE(0, 0, false, 0, 0, 0);
        GPHASE(1, 0, false, 1, 0, 2);
        GPHASE(0, 1, false, 0, 1, 0);
        GPHASE(1, 1, false, 1, 1, 0);
    }

#pragma unroll
    for (int m = 0; m < 8; ++m) {
#pragma unroll
        for (int n = 0; n < 4; ++n) {
            const int col = n0 + wc * 64 + n * 16 + lr;
#pragma unroll
            for (int rr = 0; rr < 4; ++rr) {
                const int row = row0 + wr * 128 + m * 16 + lk * 4 + rr;
                dout[(size_t)row * 4096 + 3072 + col] =
                    f2bf(sigmoidf(acc[m][n][rr] + bvreg[n]));
            }
        }
    }
}

// --- 4. tree expansion: 1 row/wave, plain stores, XCD-matched rows ---------
// gemm XCD c wrote d rows [c*2048,(c+1)*2048); expand block eb (XCD eb&7)
// takes rows from that range via ebs = (eb&7)*512 + (eb>>3) (bijective).
__global__ __launch_bounds__(256) void expand_tree(float* __restrict__ out) {
    const int t = threadIdx.x, l = t & 63, w = t >> 6;
    const int eb = blockIdx.x;
    const int ebs = (eb & 7) * 512 + (eb >> 3);    // 4096 = 8*512
    const int row = ebs * 4 + w;
    const unsigned short* dr =
        (const unsigned short*)out + (size_t)row * 4096 + 3072;
    float* orow = out + (size_t)row * OUTC;

    // ---- load ALL d into registers first ----------------------------------
    float dpath[6];
#pragma unroll
    for (int j = 0; j <= 5; ++j) {
        int idx = l >> (5 - j);
        dpath[j] = bf2f(dr[(1 << j) + (idx >> 1)]);
    }
    float d6 = bf2f(dr[64 + l]);
    unsigned int u7 = *(const unsigned int*)(dr + 128 + 2 * l);
    float d7[2] = { bf2f((unsigned short)(u7 & 0xffff)),
                    bf2f((unsigned short)(u7 >> 16)) };
    uint2 u8 = *(const uint2*)(dr + 256 + 4 * l);
    float d8[4] = { bf2f((unsigned short)(u8.x & 0xffff)),
                    bf2f((unsigned short)(u8.x >> 16)),
                    bf2f((unsigned short)(u8.y & 0xffff)),
                    bf2f((unsigned short)(u8.y >> 16)) };
    uint4 u9 = *(const uint4*)(dr + 512 + 8 * l);
    float d9[8] = { bf2f((unsigned short)(u9.x & 0xffff)),
                    bf2f((unsigned short)(u9.x >> 16)),
                    bf2f((unsigned short)(u9.y & 0xffff)),
                    bf2f((unsigned short)(u9.y >> 16)),
                    bf2f((unsigned short)(u9.z & 0xffff)),
                    bf2f((unsigned short)(u9.z >> 16)),
                    bf2f((unsigned short)(u9.w & 0xffff)),
                    bf2f((unsigned short)(u9.w >> 16)) };

    // ---- compute + store (plain stores: L2 write-combining) ---------------
    float p = 1.0f;
#pragma unroll
    for (int j = 0; j <= 5; ++j) {
        int idx = l >> (5 - j);
        p *= (idx & 1) ? (1.0f - dpath[j]) : dpath[j];
        if ((l & ((1 << (5 - j)) - 1)) == 0)
            orow[(2 << j) + idx] = p;
    }
    if (l < 2) orow[l] = 1.0f;

    float v6[2] = { p * d6, p * (1.0f - d6) };
    *(float2*)(orow + 128 + 2 * l) = make_float2(v6[0], v6[1]);

    float v7[4];
#pragma unroll
    for (int e = 0; e < 4; ++e)
        v7[e] = v6[e >> 1] * ((e & 1) ? (1.0f - d7[e >> 1]) : d7[e >> 1]);
    *(float4*)(orow + 256 + 4 * l) = make_float4(v7[0], v7[1], v7[2], v7[3]);

    float v8[8];
#pragma unroll
    for (int e = 0; e < 8; ++e)
        v8[e] = v7[e >> 1] * ((e & 1) ? (1.0f - d8[e >> 1]) : d8[e >> 1]);
    *(float4*)(orow + 512 + 8 * l)     = make_float4(v8[0], v8[1], v8[2], v8[3]);
    *(float4*)(orow + 512 + 8 * l + 4) = make_float4(v8[4], v8[5], v8[6], v8[7]);

    float v9[16];
#pragma unroll
    for (int e = 0; e < 16; ++e)
        v9[e] = v8[e >> 1] * ((e & 1) ? (1.0f - d9[e >> 1]) : d9[e >> 1]);
#pragma unroll
    for (int q = 0; q < 4; ++q)
        *(float4*)(orow + 1024 + 16 * l + 4 * q) =
            make_float4(v9[4*q], v9[4*q+1], v9[4*q+2], v9[4*q+3]);
}

// --- fallback (tiny workspace): naive fused, one row per block -------------
template <bool HAS_IDX>
__global__ __launch_bounds__(256) void fused_naive(const float* __restrict__ x,
                                                   const float* __restrict__ fm,
                                                   const float* __restrict__ W,
                                                   const float* __restrict__ bias,
                                                   const int* __restrict__ idx,
                                                   float* __restrict__ out) {
    __shared__ float fx[1024];
    __shared__ float dsm[1024];
    __shared__ float tre[2048];
    __shared__ int   idl[1024];
    const int t = threadIdx.x;
    const int row = blockIdx.x;

    if (HAS_IDX) {
        for (int k = t; k < 1024; k += 256) idl[k] = idx[k];
    } else {
        for (int k = t; k < 1024; k += 256) {
            int found = 0;
            for (int f = 0; f < 1024; ++f)
                if (fm[(size_t)f * NLEAF + k] > 0.5f) found = f;
            idl[k] = found;
        }
    }
    __syncthreads();
    const float* xr = x + (size_t)row * FEAT;
    for (int k = t; k < 1024; k += 256) fx[k] = xr[idl[k]];
    __syncthreads();

    float a0 = 0.f, a1 = 0.f, a2 = 0.f, a3 = 0.f;
    for (int k = 0; k < 1024; ++k) {
        float f = fx[k];
        const float* wrp = W + (size_t)k * NLEAF + t;
        a0 = fmaf(f, wrp[0],   a0);
        a1 = fmaf(f, wrp[256], a1);
        a2 = fmaf(f, wrp[512], a2);
        a3 = fmaf(f, wrp[768], a3);
    }
    dsm[t]       = sigmoidf(a0 + bias[t]);
    dsm[t + 256] = sigmoidf(a1 + bias[t + 256]);
    dsm[t + 512] = sigmoidf(a2 + bias[t + 512]);
    dsm[t + 768] = sigmoidf(a3 + bias[t + 768]);
    if (t < 2) tre[t] = 1.0f;
    __syncthreads();

    for (int L = 0; L < 10; ++L) {
        int n = 2 << L;
        for (int k = t; k < n; k += 256) {
            int node = (1 << L) + (k >> 1);
            float dv = dsm[node];
            tre[n + k] = tre[node] * ((k & 1) ? (1.0f - dv) : dv);
        }
        __syncthreads();
    }
    float4* orow = (float4*)(out + (size_t)row * OUTC);
    const float4* ts = (const float4*)tre;
    for (int i = t; i < 512; i += 256) orow[i] = ts[i];
}

extern "C" void kernel_launch(void* const* d_in, const int* in_sizes, int n_in,
                              void* d_out, int out_size, void* d_ws, size_t ws_size,
                              hipStream_t stream) {
    const float* x    = (const float*)d_in[0];
    const float* fm   = (const float*)d_in[1];
    const float* W    = (const float*)d_in[2];
    const float* bias = (const float*)d_in[3];
    float* out = (float*)d_out;

    const size_t IDX_B   = 4096;
    const size_t WT_B    = (size_t)NLEAF * FEAT * 2;        // 2 MiB
    const size_t FEATS_B = (size_t)BATCH * FEAT * 2;        // 32 MiB
    const size_t need = IDX_B + WT_B + FEATS_B;

    if (ws_size >= need) {
        int*   idx   = (int*)d_ws;
        short* Wt    = (short*)((char*)d_ws + IDX_B);
        short* feats = (short*)((char*)d_ws + IDX_B + WT_B);

        prep_w<<<1280, 256, 0, stream>>>(fm, W, idx, Wt);
        gather_feats<<<BATCH / 8, 256, 0, stream>>>(x, idx, feats);
        gemm256_sig_d<<<(BATCH / 256) * (NLEAF / 256), 512, 0, stream>>>(
            feats, Wt, bias, (unsigned short*)out);
        expand_tree<<<BATCH / 4, 256, 0, stream>>>(out);
    } else if (ws_size >= IDX_B) {
        int* idx = (int*)d_ws;
        prep_w<<<1280, 256, 0, stream>>>(fm, nullptr, idx, nullptr);
        fused_naive<true><<<BATCH, 256, 0, stream>>>(x, fm, W, bias, idx, out);
    } else {
        fused_naive<false><<<BATCH, 256, 0, stream>>>(x, fm, W, bias, nullptr, out);
    }
}